// Round 4
// baseline (300.586 us; speedup 1.0000x reference)
//
#include <hip/hip_runtime.h>
#include <math.h>

#define NROWS 8192
#define NCOLS 4096
#define NC4 1024          // NCOLS/4
#define EPS 1e-8f

// Scratch in device globals: graph-capture safe, fully re-written every call.
__device__ float g_partials[256 * NCOLS];  // [rowgroup][col] partials, 4 MB
__device__ float g_S[NCOLS];               // masked column sums
__device__ float g_n0[256];                // per-rowgroup label-0 counts
__device__ float g_msq[64];                // per-block ||S||^2 partials
__device__ float g_Aacc, g_Bacc;           // atomic accumulators
__device__ int   g_cnt;                    // last-block-done counter

// ---- K1: masked column partial sums (1024 blocks x 256) ----
// Block b: rowgroup rg=b>>2 (32 rows), column quarter q=b&3 (256 float4 cols).
// Compact masked-row index list removes branches from the hot loop.
__global__ __launch_bounds__(256) void k_colsum(const float* __restrict__ labels,
                                                const float* __restrict__ datas) {
    const int b = blockIdx.x, t = threadIdx.x;
    const int rg = b >> 2, q = b & 3;
    const int r0 = rg * 32;
    __shared__ float m[32];
    __shared__ int idx[32];
    __shared__ int cntS;
    if (t < 32) {
        float l0 = labels[2 * (r0 + t)];
        float l1 = labels[2 * (r0 + t) + 1];
        m[t] = (l0 >= l1) ? 1.f : 0.f;     // argmax ties -> index 0
    }
    __syncthreads();
    if (t == 0) {
        int c = 0;
        #pragma unroll
        for (int r = 0; r < 32; ++r) if (m[r] != 0.f) idx[c++] = r0 + r;
        cntS = c;
        if (q == 0) g_n0[rg] = (float)c;
    }
    __syncthreads();
    const int cnt = cntS;
    const int coff = q * 256 + t;
    const float4* d4 = (const float4*)datas;
    float4 a0 = {0,0,0,0}, a1 = {0,0,0,0}, a2 = {0,0,0,0}, a3 = {0,0,0,0};
    int j = 0;
    for (; j + 3 < cnt; j += 4) {
        float4 v0 = d4[(size_t)idx[j]     * NC4 + coff];
        float4 v1 = d4[(size_t)idx[j + 1] * NC4 + coff];
        float4 v2 = d4[(size_t)idx[j + 2] * NC4 + coff];
        float4 v3 = d4[(size_t)idx[j + 3] * NC4 + coff];
        a0.x += v0.x; a0.y += v0.y; a0.z += v0.z; a0.w += v0.w;
        a1.x += v1.x; a1.y += v1.y; a1.z += v1.z; a1.w += v1.w;
        a2.x += v2.x; a2.y += v2.y; a2.z += v2.z; a2.w += v2.w;
        a3.x += v3.x; a3.y += v3.y; a3.z += v3.z; a3.w += v3.w;
    }
    for (; j < cnt; ++j) {
        float4 v = d4[(size_t)idx[j] * NC4 + coff];
        a0.x += v.x; a0.y += v.y; a0.z += v.z; a0.w += v.w;
    }
    a0.x += a1.x + a2.x + a3.x;
    a0.y += a1.y + a2.y + a3.y;
    a0.z += a1.z + a2.z + a3.z;
    a0.w += a1.w + a2.w + a3.w;
    ((float4*)g_partials)[(size_t)rg * NC4 + coff] = a0;
}

// ---- K2: reduce partials -> S, ||S||^2 partials (64 blocks x 1024) ----
__global__ __launch_bounds__(1024) void k_reduceS() {
    const int t = threadIdx.x, b = blockIdx.x;
    if (b == 0 && t == 0) { g_Aacc = 0.f; g_Bacc = 0.f; g_cnt = 0; }
    const int col = t & 63, sub = t >> 6;   // 16 subs x 16 rowgroups each
    const int c = b * 64 + col;
    float s = 0.f;
    #pragma unroll
    for (int j = 0; j < 16; ++j)
        s += g_partials[(size_t)(sub * 16 + j) * NCOLS + c];
    __shared__ float sh[16][65];
    sh[sub][col] = s;
    __syncthreads();
    if (t < 64) {                           // exactly one wave
        float tot = 0.f;
        #pragma unroll
        for (int i = 0; i < 16; ++i) tot += sh[i][t];
        g_S[c] = tot;
        float sq = tot * tot;
        #pragma unroll
        for (int off = 32; off; off >>= 1) sq += __shfl_xor(sq, off);
        if (t == 0) g_msq[b] = sq;
    }
}

// ---- K3: per-row |dot|/xnorm + fused final (2048 blocks x 256) ----
__global__ __launch_bounds__(256) void k_cos(const float* __restrict__ labels,
                                             const float* __restrict__ datas,
                                             float* __restrict__ out) {
    const int t = threadIdx.x, lane = t & 63, w = t >> 6;
    const int r = blockIdx.x * 4 + w;
    __shared__ float4 sS[NC4];              // S staged in LDS (16 KB)
    const float4* s4g = (const float4*)g_S;
    #pragma unroll
    for (int k = 0; k < 4; ++k) sS[t + k * 256] = s4g[t + k * 256];
    __syncthreads();

    const float4* d4 = (const float4*)datas;
    const size_t base = (size_t)r * NC4;
    float dot = 0.f, sq = 0.f;
    float4 v[8];
    #pragma unroll
    for (int half = 0; half < 2; ++half) {
        #pragma unroll
        for (int k = 0; k < 8; ++k)
            v[k] = d4[base + lane + ((half * 8 + k) << 6)];
        #pragma unroll
        for (int k = 0; k < 8; ++k) {
            float4 sv = sS[lane + ((half * 8 + k) << 6)];
            dot += v[k].x * sv.x + v[k].y * sv.y + v[k].z * sv.z + v[k].w * sv.w;
            sq  += v[k].x * v[k].x + v[k].y * v[k].y + v[k].z * v[k].z + v[k].w * v[k].w;
        }
    }
    #pragma unroll
    for (int off = 32; off; off >>= 1) {
        dot += __shfl_xor(dot, off);
        sq  += __shfl_xor(sq, off);
    }
    __shared__ float shA[4], shB[4];
    __shared__ int shLast;
    if (lane == 0) {
        float a = fabsf(dot) / fmaxf(sqrtf(sq), EPS);  // |dot|/||x||; /||S|| later
        float l0 = labels[2 * r], l1 = labels[2 * r + 1];
        bool m0 = (l0 >= l1);
        shA[w] = m0 ? a : 0.f;
        shB[w] = m0 ? 0.f : a;
    }
    __syncthreads();
    if (t == 0) {
        atomicAdd(&g_Aacc, shA[0] + shA[1] + shA[2] + shA[3]);
        atomicAdd(&g_Bacc, shB[0] + shB[1] + shB[2] + shB[3]);
        __threadfence();
        int old = atomicAdd(&g_cnt, 1);
        shLast = (old == gridDim.x - 1) ? 1 : 0;
    }
    __syncthreads();
    if (shLast) {
        // ---- fused final reduction (runs in exactly one block) ----
        __threadfence();
        float n0 = g_n0[t & 255];           // 256 values
        float msq = (t < 64) ? g_msq[t] : 0.f;
        if (t >= 256) n0 = 0.f;             // (t<256 always true; keep safe)
        #pragma unroll
        for (int off = 32; off; off >>= 1) {
            n0  += __shfl_xor(n0, off);
            msq += __shfl_xor(msq, off);
        }
        __shared__ float shn[4], shm2[4];
        if (lane == 0) { shn[w] = n0; shm2[w] = msq; }
        __syncthreads();
        if (t == 0) {
            float n0t = shn[0] + shn[1] + shn[2] + shn[3];
            float mt  = shm2[0] + shm2[1] + shm2[2] + shm2[3];
            float At = atomicAdd(&g_Aacc, 0.f);
            float Bt = atomicAdd(&g_Bacc, 0.f);
            float n1 = (float)NROWS - n0t;
            float n0d = fmaxf(n0t, 1.f), n1d = fmaxf(n1, 1.f);
            // n0d * max(||S||/n0d, eps) == max(||S||, n0d*eps)
            float D = fmaxf(sqrtf(mt), n0d * EPS);
            float simL = (n0t > 0.f) ? (n0t - At / D) / n0d : 0.f;
            float difL = (n0t > 0.f && n1 > 0.f) ? (Bt / D) / n1d : 0.f;
            out[0] = simL + difL;
            out[1] = simL;
            out[2] = difL;
        }
    }
}

extern "C" void kernel_launch(void* const* d_in, const int* in_sizes, int n_in,
                              void* d_out, int out_size, void* d_ws, size_t ws_size,
                              hipStream_t stream) {
    const float* labels = (const float*)d_in[0];
    const float* datas  = (const float*)d_in[1];
    float* out = (float*)d_out;

    k_colsum<<<1024, 256, 0, stream>>>(labels, datas);
    k_reduceS<<<64, 1024, 0, stream>>>();
    k_cos<<<2048, 256, 0, stream>>>(labels, datas, out);
}

// Round 5
// 206.461 us; speedup vs baseline: 1.4559x; 1.4559x over previous
//
#include <hip/hip_runtime.h>
#include <math.h>

#define NROWS 8192
#define NCOLS 4096
#define NC4 1024          // NCOLS/4
#define EPS 1e-8f

// Scratch in device globals: graph-capture safe, fully re-written every call.
__device__ float g_partials[256 * NCOLS];  // [rowgroup][col] partials, 4 MB
__device__ float g_S[NCOLS];               // masked column sums
__device__ float g_n0[256];                // per-rowgroup label-0 counts
__device__ float g_msq[64];                // per-block ||S||^2 partials
__device__ float g_A[2048];                // per-block sum mask0 * |dot|/xnorm
__device__ float g_B[2048];                // per-block sum mask1 * |dot|/xnorm

// ---- K1: masked column partial sums (1024 blocks x 256) ----
// Block b: rowgroup rg=b>>2 (32 rows), column quarter q=b&3 (256 float4 cols).
// 4 blocks/CU averages out the binomial row-count imbalance that bound the
// R3 one-block-per-CU version; compact index list debranches the hot loop.
__global__ __launch_bounds__(256) void k_colsum(const float* __restrict__ labels,
                                                const float* __restrict__ datas) {
    const int b = blockIdx.x, t = threadIdx.x;
    const int rg = b >> 2, q = b & 3;
    const int r0 = rg * 32;
    __shared__ float m[32];
    __shared__ int idx[32];
    __shared__ int cntS;
    if (t < 32) {
        float l0 = labels[2 * (r0 + t)];
        float l1 = labels[2 * (r0 + t) + 1];
        m[t] = (l0 >= l1) ? 1.f : 0.f;     // argmax ties -> index 0
    }
    __syncthreads();
    if (t == 0) {
        int c = 0;
        #pragma unroll
        for (int r = 0; r < 32; ++r) if (m[r] != 0.f) idx[c++] = r0 + r;
        cntS = c;
        if (q == 0) g_n0[rg] = (float)c;
    }
    __syncthreads();
    const int cnt = cntS;
    const int coff = q * 256 + t;
    const float4* d4 = (const float4*)datas;
    float4 a0 = {0,0,0,0}, a1 = {0,0,0,0}, a2 = {0,0,0,0}, a3 = {0,0,0,0};
    int j = 0;
    for (; j + 3 < cnt; j += 4) {
        float4 v0 = d4[(size_t)idx[j]     * NC4 + coff];
        float4 v1 = d4[(size_t)idx[j + 1] * NC4 + coff];
        float4 v2 = d4[(size_t)idx[j + 2] * NC4 + coff];
        float4 v3 = d4[(size_t)idx[j + 3] * NC4 + coff];
        a0.x += v0.x; a0.y += v0.y; a0.z += v0.z; a0.w += v0.w;
        a1.x += v1.x; a1.y += v1.y; a1.z += v1.z; a1.w += v1.w;
        a2.x += v2.x; a2.y += v2.y; a2.z += v2.z; a2.w += v2.w;
        a3.x += v3.x; a3.y += v3.y; a3.z += v3.z; a3.w += v3.w;
    }
    for (; j < cnt; ++j) {
        float4 v = d4[(size_t)idx[j] * NC4 + coff];
        a0.x += v.x; a0.y += v.y; a0.z += v.z; a0.w += v.w;
    }
    a0.x += a1.x + a2.x + a3.x;
    a0.y += a1.y + a2.y + a3.y;
    a0.z += a1.z + a2.z + a3.z;
    a0.w += a1.w + a2.w + a3.w;
    ((float4*)g_partials)[(size_t)rg * NC4 + coff] = a0;
}

// ---- K2: reduce partials -> S, ||S||^2 partials (64 blocks x 1024) ----
__global__ __launch_bounds__(1024) void k_reduceS() {
    const int t = threadIdx.x, b = blockIdx.x;
    const int col = t & 63, sub = t >> 6;   // 16 subs x 16 rowgroups each
    const int c = b * 64 + col;
    float s = 0.f;
    #pragma unroll
    for (int j = 0; j < 16; ++j)
        s += g_partials[(size_t)(sub * 16 + j) * NCOLS + c];
    __shared__ float sh[16][65];
    sh[sub][col] = s;
    __syncthreads();
    if (t < 64) {                           // exactly one wave
        float tot = 0.f;
        #pragma unroll
        for (int i = 0; i < 16; ++i) tot += sh[i][t];
        g_S[c] = tot;
        float sq = tot * tot;
        #pragma unroll
        for (int off = 32; off; off >>= 1) sq += __shfl_xor(sq, off);
        if (t == 0) g_msq[b] = sq;
    }
}

// ---- K3: per-row |dot|/xnorm (2048 blocks x 256, one wave per row) ----
// No LDS staging of S (L1 serves it), no atomics/fences (R4 regression).
__global__ __launch_bounds__(256) void k_cos(const float* __restrict__ labels,
                                             const float* __restrict__ datas) {
    const int t = threadIdx.x, lane = t & 63, w = t >> 6;
    const int r = blockIdx.x * 4 + w;
    const float4* d4 = (const float4*)datas;
    const float4* s4 = (const float4*)g_S;
    const size_t base = (size_t)r * NC4;
    float dot = 0.f, sq = 0.f;
    float4 v[8];
    #pragma unroll
    for (int half = 0; half < 2; ++half) {
        #pragma unroll
        for (int k = 0; k < 8; ++k)
            v[k] = d4[base + lane + ((half * 8 + k) << 6)];
        #pragma unroll
        for (int k = 0; k < 8; ++k) {
            float4 sv = s4[lane + ((half * 8 + k) << 6)];
            dot += v[k].x * sv.x + v[k].y * sv.y + v[k].z * sv.z + v[k].w * sv.w;
            sq  += v[k].x * v[k].x + v[k].y * v[k].y + v[k].z * v[k].z + v[k].w * v[k].w;
        }
    }
    #pragma unroll
    for (int off = 32; off; off >>= 1) {
        dot += __shfl_xor(dot, off);
        sq  += __shfl_xor(sq, off);
    }
    __shared__ float shA[4], shB[4];
    if (lane == 0) {
        float a = fabsf(dot) / fmaxf(sqrtf(sq), EPS);  // |dot|/||x|| ; /||S|| later
        float l0 = labels[2 * r], l1 = labels[2 * r + 1];
        bool m0 = (l0 >= l1);
        shA[w] = m0 ? a : 0.f;
        shB[w] = m0 ? 0.f : a;
    }
    __syncthreads();
    if (t == 0) {
        g_A[blockIdx.x] = shA[0] + shA[1] + shA[2] + shA[3];
        g_B[blockIdx.x] = shB[0] + shB[1] + shB[2] + shB[3];
    }
}

// ---- K4: final scalar reduction -> 3 outputs (1 block x 1024) ----
__global__ __launch_bounds__(1024) void k_final(float* __restrict__ out) {
    const int t = threadIdx.x, lane = t & 63, w = t >> 6;
    float A = g_A[t] + g_A[t + 1024];
    float B = g_B[t] + g_B[t + 1024];
    float n0 = (t < 256) ? g_n0[t] : 0.f;
    float msq = (t < 64) ? g_msq[t] : 0.f;
    #pragma unroll
    for (int off = 32; off; off >>= 1) {
        A   += __shfl_xor(A, off);
        B   += __shfl_xor(B, off);
        n0  += __shfl_xor(n0, off);
        msq += __shfl_xor(msq, off);
    }
    __shared__ float sh[16][4];
    if (lane == 0) { sh[w][0] = A; sh[w][1] = B; sh[w][2] = n0; sh[w][3] = msq; }
    __syncthreads();
    if (t == 0) {
        float At = 0.f, Bt = 0.f, n0t = 0.f, mt = 0.f;
        #pragma unroll
        for (int i = 0; i < 16; ++i) {
            At += sh[i][0]; Bt += sh[i][1]; n0t += sh[i][2]; mt += sh[i][3];
        }
        float n1 = (float)NROWS - n0t;
        float n0d = fmaxf(n0t, 1.f), n1d = fmaxf(n1, 1.f);
        // n0d * max(||S||/n0d, eps) == max(||S||, n0d*eps)
        float D = fmaxf(sqrtf(mt), n0d * EPS);
        float simL = (n0t > 0.f) ? (n0t - At / D) / n0d : 0.f;
        float difL = (n0t > 0.f && n1 > 0.f) ? (Bt / D) / n1d : 0.f;
        out[0] = simL + difL;
        out[1] = simL;
        out[2] = difL;
    }
}

extern "C" void kernel_launch(void* const* d_in, const int* in_sizes, int n_in,
                              void* d_out, int out_size, void* d_ws, size_t ws_size,
                              hipStream_t stream) {
    const float* labels = (const float*)d_in[0];
    const float* datas  = (const float*)d_in[1];
    float* out = (float*)d_out;

    k_colsum<<<1024, 256, 0, stream>>>(labels, datas);
    k_reduceS<<<64, 1024, 0, stream>>>();
    k_cos<<<2048, 256, 0, stream>>>(labels, datas);
    k_final<<<1, 1024, 0, stream>>>(out);
}